// Round 6
// baseline (194.200 us; speedup 1.0000x reference)
//
#include <hip/hip_runtime.h>
#include <math.h>

// Problem constants (fixed by reference)
constexpr int Bn = 4, Ln = 2048, DM = 512, NH = 8, DKv = 32, INNER = 256;
constexpr int TTOK = Bn * Ln;                              // 8192 tokens
constexpr size_t HEAD_ELEMS = (size_t)Bn * NH * Ln * DKv;  // 2,097,152 elems per Q/K/V

// Workspace layout (shorts):
//  [0,2M)   Qh bf16 [n,h,l,d]  (PRE-SCALED by log2(e)/sqrt(32))
//  [2M,4M)  Kh bf16 [n,h,l,d]
//  [4M,6M)  Vt bf16 [n,h,d,l]
//  [6M,8M)  O2b bf16 [tok][256]
//  [8M,12.2M)  Xb bf16 [tok][512]
//  [12.25M, +393216)  Wb bf16 (Wq|Wk|Wv)
//  [+131072]          Wfcb bf16

typedef short short8 __attribute__((ext_vector_type(8)));   // 8 bf16 (4 VGPRs)
typedef short short4v __attribute__((ext_vector_type(4)));  // 4 bf16 (2 VGPRs)
typedef float floatx4 __attribute__((ext_vector_type(4)));  // MFMA C/D frag

constexpr size_t XB_OFF  = 8u * 1024 * 1024;        // shorts
constexpr size_t WB_OFF  = 12536832;                // shorts, 16B aligned
constexpr size_t WFCB_OFF = WB_OFF + 3 * 131072;

constexpr float C1 = 0.25505654f;  // log2(e)/sqrt(32), folded into Qh at projection

__device__ inline short f2bf(float x) {                     // RNE f32->bf16
  unsigned u = __builtin_bit_cast(unsigned, x);
  unsigned r = (u + 0x7FFFu + ((u >> 16) & 1u)) >> 16;
  return (short)r;
}

// K=16 bf16 MFMA: A[m=lane&15][k=quad*4+j], B[k=quad*4+j][n=lane&15], C/D as usual.
#if __has_builtin(__builtin_amdgcn_mfma_f32_16x16x16bf16_1k)
#define MFMA16(a, b, c) __builtin_amdgcn_mfma_f32_16x16x16bf16_1k(a, b, c, 0, 0, 0)
#else
__device__ inline floatx4 mfma16_asm(short4v a, short4v b, floatx4 c) {
  asm volatile("v_mfma_f32_16x16x16_bf16 %0, %1, %2, %3\n\ts_nop 4"
               : "=v"(c) : "v"(a), "v"(b), "0"(c));
  return c;
}
#define MFMA16(a, b, c) mfma16_asm(a, b, c)
#endif

// ---------------- Weight pre-convert: fp32 -> bf16 ----------------
__global__ __launch_bounds__(256) void cvtw_kernel(
    const float* __restrict__ Wq, const float* __restrict__ Wk,
    const float* __restrict__ Wv, const float* __restrict__ Wfc,
    short* __restrict__ Wb, short* __restrict__ Wfcb)
{
  const int z = blockIdx.y;
  const float* src = z == 0 ? Wq : (z == 1 ? Wk : (z == 2 ? Wv : Wfc));
  short* dst = z < 3 ? Wb + (size_t)z * 131072 : Wfcb;
  const int idx = (blockIdx.x * 256 + threadIdx.x) * 4;   // 131072 elems, grid.x=128
  float4 x = *(const float4*)&src[idx];
  *(short4v*)&dst[idx] = (short4v){f2bf(x.x), f2bf(x.y), f2bf(x.z), f2bf(x.w)};
}

// ---------------- Projection (bf16 MFMA, reg-double-buffered) ----------------
// grid (TTOK/64, INNER/64, 3), block 256 = 4 waves. Q output pre-scaled by C1.
__global__ __launch_bounds__(256) void proj_kernel(
    const float* __restrict__ q, const float* __restrict__ k, const float* __restrict__ v,
    const short* __restrict__ Wb,
    const float* __restrict__ bq, const float* __restrict__ bk,
    const float* __restrict__ bv,
    short* __restrict__ ws)
{
  const int mat = blockIdx.z;
  const float* X    = mat == 0 ? q  : (mat == 1 ? k  : v);
  const short* W    = Wb + (size_t)mat * 131072;
  const float* bias = mat == 0 ? bq : (mat == 1 ? bk : bv);
  short* outp = ws + (size_t)mat * HEAD_ELEMS;

  const int t0 = blockIdx.x * 64;
  const int c0 = blockIdx.y * 64;
  const int tid = threadIdx.x;
  const int col = tid & 15;
  const int quad = (tid & 63) >> 4;
  const int w = tid >> 6;

  __shared__ short Xs[64 * 136];
  __shared__ short Wsh[64 * 136];

  floatx4 acc[4];
#pragma unroll
  for (int nj = 0; nj < 4; ++nj) acc[nj] = (floatx4){0.f, 0.f, 0.f, 0.f};

  float4 xr[8];
  short8 wr[4];
  auto loadX = [&](int k0) {
#pragma unroll
    for (int j = 0; j < 8; ++j) {
      const int i = tid + j * 256, row = i >> 5, c4 = i & 31;
      xr[j] = *(const float4*)&X[(size_t)(t0 + row) * DM + k0 + c4 * 4];
    }
  };
  auto loadW = [&](int k0) {
#pragma unroll
    for (int j = 0; j < 4; ++j) {
      const int s = tid + j * 256, row = s >> 4, k8 = s & 15;
      wr[j] = *(const short8*)&W[(size_t)(c0 + row) * DM + k0 + k8 * 8];
    }
  };

  loadX(0);
  loadW(0);

  for (int kc = 0; kc < 4; ++kc) {
#pragma unroll
    for (int j = 0; j < 8; ++j) {
      const int i = tid + j * 256, row = i >> 5, c4 = i & 31;
      *(short4v*)&Xs[row * 136 + c4 * 4] =
          (short4v){f2bf(xr[j].x), f2bf(xr[j].y), f2bf(xr[j].z), f2bf(xr[j].w)};
    }
#pragma unroll
    for (int j = 0; j < 4; ++j) {
      const int s = tid + j * 256, row = s >> 4, k8 = s & 15;
      *(short8*)&Wsh[row * 136 + k8 * 8] = wr[j];
    }
    __syncthreads();
    if (kc < 3) {                       // prefetch next chunk while MFMAs run
      loadX((kc + 1) * 128);
      loadW((kc + 1) * 128);
    }
#pragma unroll
    for (int ks = 0; ks < 4; ++ks) {
      short8 a = *(const short8*)&Xs[(w * 16 + col) * 136 + ks * 32 + quad * 8];
#pragma unroll
      for (int nj = 0; nj < 4; ++nj) {
        short8 b = *(const short8*)&Wsh[(nj * 16 + col) * 136 + ks * 32 + quad * 8];
        acc[nj] = __builtin_amdgcn_mfma_f32_16x16x32_bf16(a, b, acc[nj], 0, 0, 0);
      }
    }
    __syncthreads();
  }

#pragma unroll
  for (int nj = 0; nj < 4; ++nj) {
#pragma unroll
    for (int r = 0; r < 4; ++r) {
      const int t = t0 + w * 16 + quad * 4 + r;
      const int n = t >> 11, ll = t & (Ln - 1);
      const int c = c0 + nj * 16 + col;
      const int d = c >> 3, h = c & 7;           // head is FASTEST dim of proj col
      float pv = acc[nj][r] + bias[c];
      if (mat == 0) pv *= C1;                    // fold softmax scale into Q
      const short val = f2bf(pv);
      if (mat < 2)
        outp[((size_t)(n * NH + h) * Ln + ll) * DKv + d] = val;   // [n,h,l,d]
      else
        outp[((size_t)(n * NH + h) * DKv + d) * Ln + ll] = val;   // [n,h,d,l]
    }
  }
}

// ---------------- Attention: register-P flash, conflict-free LDS, 1 barrier/iter ----------------
// grid (Ln/64, Bn*NH), block 256 = 4 waves, 16 q per wave. St = K·Q^T (16x16x32);
// P in registers; O^T = V^T·P (16x16x16). V repacked in LDS as [ks][quad][col][half][r]
// so PV A-frags are single conflict-free b128 reads (start bank 4*(col%8), 8 disjoint
// 4-bank groups). Double-buffered LDS -> one barrier per 64-key chunk.
__global__ __launch_bounds__(256) void attn_kernel(const short* __restrict__ ws,
                                                   short* __restrict__ O2b)
{
  const int bh = blockIdx.y;
  const int n = bh >> 3, h = bh & 7;
  const int tid = threadIdx.x;
  const int col = tid & 15;
  const int quad = (tid & 63) >> 4;
  const int w = tid >> 6;
  const int qi = blockIdx.x * 64 + w * 16 + col;   // this lane's q row

  const short* Qh = ws;
  const short* Kg = ws + HEAD_ELEMS + (size_t)bh * Ln * DKv;      // [l][d]
  const short* Vg = ws + 2 * HEAD_ELEMS + (size_t)bh * DKv * Ln;  // [d][l]

  __shared__ short Ks[2][64 * 32];   // [key][d]
  __shared__ short Vs[2][64 * 32];   // [ks][quad][col][half][r] interleave

  // Q as B-frag (pre-scaled by C1): B[k=d=quad*8+j][n=q=lane&15]
  const short8 aq = *(const short8*)&Qh[(size_t)bh * Ln * DKv + (size_t)qi * DKv + quad * 8];

  float lsum = 0.f;
  floatx4 o[2];
  o[0] = (floatx4){0.f, 0.f, 0.f, 0.f};
  o[1] = (floatx4){0.f, 0.f, 0.f, 0.f};

  // V staging: thread (vd, vkb) reads V^T[vd][kb*8..+7], scatters 2x short4v.
  const int vd = tid >> 3, vkb = tid & 7;
  const int voff1 = (vkb >> 1) * 512 + ((2 * vkb) & 3) * 128 + (vd & 15) * 8 + (vd >> 4) * 4;
  const int voff2 = (vkb >> 1) * 512 + ((2 * vkb + 1) & 3) * 128 + (vd & 15) * 8 + (vd >> 4) * 4;

  short8 kr = *(const short8*)(Kg + tid * 8);
  short8 vr = *(const short8*)(Vg + (size_t)vd * Ln + vkb * 8);

  for (int kt = 0; kt < 32; ++kt) {
    short* ksb = Ks[kt & 1];
    short* vsb = Vs[kt & 1];
    *(short8*)&ksb[tid * 8] = kr;
    *(short4v*)&vsb[voff1] = __builtin_shufflevector(vr, vr, 0, 1, 2, 3);
    *(short4v*)&vsb[voff2] = __builtin_shufflevector(vr, vr, 4, 5, 6, 7);
    __syncthreads();
    if (kt < 31) {                       // prefetch next chunk into registers
      kr = *(const short8*)(Kg + (size_t)(kt + 1) * 2048 + tid * 8);
      vr = *(const short8*)(Vg + (size_t)vd * Ln + (kt + 1) * 64 + vkb * 8);
    }

    // St tiles: rows = keys (quad*4+r), cols = q (lane&15); already log2-scaled
    floatx4 s[4];
    const floatx4 z4 = {0.f, 0.f, 0.f, 0.f};
#pragma unroll
    for (int ks = 0; ks < 4; ++ks) {
      short8 kf = *(const short8*)&ksb[(ks * 16 + col) * 32 + quad * 8];
      s[ks] = __builtin_amdgcn_mfma_f32_16x16x32_bf16(kf, aq, z4, 0, 0, 0);
    }

    // p = exp2(s); accumulate l; pack to bf16 B-frags (truncating v_perm)
    short4v pf[4];
#pragma unroll
    for (int ks = 0; ks < 4; ++ks) {
      float p0 = __builtin_amdgcn_exp2f(s[ks][0]);
      float p1 = __builtin_amdgcn_exp2f(s[ks][1]);
      float p2 = __builtin_amdgcn_exp2f(s[ks][2]);
      float p3 = __builtin_amdgcn_exp2f(s[ks][3]);
      lsum += (p0 + p1) + (p2 + p3);
      unsigned u0 = __builtin_amdgcn_perm(__builtin_bit_cast(unsigned, p1),
                                          __builtin_bit_cast(unsigned, p0), 0x07060302u);
      unsigned u1 = __builtin_amdgcn_perm(__builtin_bit_cast(unsigned, p3),
                                          __builtin_bit_cast(unsigned, p2), 0x07060302u);
      uint2 uu = make_uint2(u0, u1);
      pf[ks] = __builtin_bit_cast(short4v, uu);
    }

    // O^T += V^T P : both d-halves in ONE b128 (conflict-free)
#pragma unroll
    for (int ks = 0; ks < 4; ++ks) {
      short8 vv = *(const short8*)&vsb[ks * 512 + quad * 128 + col * 8];
      o[0] = MFMA16(__builtin_shufflevector(vv, vv, 0, 1, 2, 3), pf[ks], o[0]);
      o[1] = MFMA16(__builtin_shufflevector(vv, vv, 4, 5, 6, 7), pf[ks], o[1]);
    }
  }

  // l: cross-quad reduce (lanes col, col+16, col+32, col+48 hold key-partitions of q)
  lsum += __shfl_xor(lsum, 16);
  lsum += __shfl_xor(lsum, 32);
  const float inv = 1.f / lsum;

  // O^T C-layout: col = q, row = quad*4 + r = d-in-tile (+16*dt)
  short* dst = &O2b[((size_t)n * Ln + qi) * INNER + h * DKv];
#pragma unroll
  for (int dt = 0; dt < 2; ++dt)
#pragma unroll
    for (int r = 0; r < 4; ++r)
      dst[dt * 16 + quad * 4 + r] = f2bf(o[dt][r] * inv);
}

// ---------------- FC (bf16 MFMA): Xb = bf16(O2b @ Wfc^T + bfc + q) ----------------
__global__ __launch_bounds__(256) void fc_kernel(
    const short* __restrict__ O2b, const short* __restrict__ Wfcb,
    const float* __restrict__ bfc, const float* __restrict__ qin,
    short* __restrict__ Xb)
{
  const int t0 = blockIdx.x * 64;
  const int c0 = blockIdx.y * 64;
  const int tid = threadIdx.x;
  const int col = tid & 15;
  const int quad = (tid & 63) >> 4;
  const int w = tid >> 6;

  __shared__ short As[64 * 264];
  __shared__ short Bs[64 * 264];

  for (int i = tid; i < 2048; i += 256) {
    const int row = i >> 5, k8 = i & 31;
    *(short8*)&As[row * 264 + k8 * 8] =
        *(const short8*)&O2b[(size_t)(t0 + row) * INNER + k8 * 8];
    *(short8*)&Bs[row * 264 + k8 * 8] =
        *(const short8*)&Wfcb[(size_t)(c0 + row) * INNER + k8 * 8];
  }
  __syncthreads();

  floatx4 acc[4];
#pragma unroll
  for (int nj = 0; nj < 4; ++nj) acc[nj] = (floatx4){0.f, 0.f, 0.f, 0.f};

#pragma unroll
  for (int ks = 0; ks < 8; ++ks) {
    short8 a = *(const short8*)&As[(w * 16 + col) * 264 + ks * 32 + quad * 8];
#pragma unroll
    for (int nj = 0; nj < 4; ++nj) {
      short8 b = *(const short8*)&Bs[(nj * 16 + col) * 264 + ks * 32 + quad * 8];
      acc[nj] = __builtin_amdgcn_mfma_f32_16x16x32_bf16(a, b, acc[nj], 0, 0, 0);
    }
  }

#pragma unroll
  for (int nj = 0; nj < 4; ++nj) {
#pragma unroll
    for (int r = 0; r < 4; ++r) {
      const int t = t0 + w * 16 + quad * 4 + r;
      const int c = c0 + nj * 16 + col;
      Xb[(size_t)t * DM + c] = f2bf(acc[nj][r] + bfc[c] + qin[(size_t)t * DM + c]);
    }
  }
}

// ---------------- LayerNorm over bf16 Xb rows -> fp32 out ----------------
__global__ __launch_bounds__(256) void ln_kernel(
    const short* __restrict__ Xb, const float* __restrict__ gamma,
    const float* __restrict__ beta, float* __restrict__ outp)
{
  const int t = blockIdx.x * 4 + (threadIdx.x >> 6);
  const int lane = threadIdx.x & 63;

  short8 xs = *(const short8*)&Xb[(size_t)t * DM + lane * 8];
  float x[8];
#pragma unroll
  for (int j = 0; j < 8; ++j)
    x[j] = __builtin_bit_cast(float, ((unsigned)(unsigned short)xs[j]) << 16);

  float s1 = 0.f, s2 = 0.f;
#pragma unroll
  for (int j = 0; j < 8; ++j) { s1 += x[j]; s2 += x[j] * x[j]; }
#pragma unroll
  for (int off = 32; off >= 1; off >>= 1) {
    s1 += __shfl_xor(s1, off);
    s2 += __shfl_xor(s2, off);
  }
  const float mean = s1 * (1.f / 512.f);
  const float var = s2 * (1.f / 512.f) - mean * mean;
  const float rstd = rsqrtf(var + 1e-5f);

  float4 g0 = *(const float4*)&gamma[lane * 8];
  float4 g1 = *(const float4*)&gamma[lane * 8 + 4];
  float4 b0 = *(const float4*)&beta[lane * 8];
  float4 b1 = *(const float4*)&beta[lane * 8 + 4];

  float4 y0, y1;
  y0.x = g0.x * (x[0] - mean) * rstd + b0.x;
  y0.y = g0.y * (x[1] - mean) * rstd + b0.y;
  y0.z = g0.z * (x[2] - mean) * rstd + b0.z;
  y0.w = g0.w * (x[3] - mean) * rstd + b0.w;
  y1.x = g1.x * (x[4] - mean) * rstd + b1.x;
  y1.y = g1.y * (x[5] - mean) * rstd + b1.y;
  y1.z = g1.z * (x[6] - mean) * rstd + b1.z;
  y1.w = g1.w * (x[7] - mean) * rstd + b1.w;

  float* drow = &outp[(size_t)t * DM + lane * 8];
  *(float4*)&drow[0] = y0;
  *(float4*)&drow[4] = y1;
}

extern "C" void kernel_launch(void* const* d_in, const int* in_sizes, int n_in,
                              void* d_out, int out_size, void* d_ws, size_t ws_size,
                              hipStream_t stream) {
  const float* q     = (const float*)d_in[0];
  const float* k     = (const float*)d_in[1];
  const float* v     = (const float*)d_in[2];
  const float* Wq    = (const float*)d_in[3];
  const float* bq    = (const float*)d_in[4];
  const float* Wk    = (const float*)d_in[5];
  const float* bk    = (const float*)d_in[6];
  const float* Wv    = (const float*)d_in[7];
  const float* bv    = (const float*)d_in[8];
  const float* Wfc   = (const float*)d_in[9];
  const float* bfc   = (const float*)d_in[10];
  const float* gamma = (const float*)d_in[11];
  const float* beta  = (const float*)d_in[12];

  short* wsS  = (short*)d_ws;
  short* O2b  = wsS + 3 * HEAD_ELEMS;
  short* Xb   = wsS + XB_OFF;
  short* Wb   = wsS + WB_OFF;
  short* Wfcb = wsS + WFCB_OFF;

  cvtw_kernel<<<dim3(128, 4), 256, 0, stream>>>(Wq, Wk, Wv, Wfc, Wb, Wfcb);

  dim3 gp(TTOK / 64, INNER / 64, 3);
  proj_kernel<<<gp, 256, 0, stream>>>(q, k, v, Wb, bq, bk, bv, wsS);

  dim3 gatt(Ln / 64, Bn * NH);
  attn_kernel<<<gatt, 256, 0, stream>>>(wsS, O2b);

  dim3 gfc(TTOK / 64, DM / 64);
  fc_kernel<<<gfc, 256, 0, stream>>>(O2b, Wfcb, bfc, q, Xb);

  ln_kernel<<<TTOK / 4, 256, 0, stream>>>(Xb, gamma, beta, (float*)d_out);
}

// Round 7
// 187.825 us; speedup vs baseline: 1.0339x; 1.0339x over previous
//
#include <hip/hip_runtime.h>
#include <math.h>

// Problem constants (fixed by reference)
constexpr int Bn = 4, Ln = 2048, DM = 512, NH = 8, DKv = 32, INNER = 256;
constexpr int TTOK = Bn * Ln;                              // 8192 tokens
constexpr size_t HEAD_ELEMS = (size_t)Bn * NH * Ln * DKv;  // 2,097,152 elems per Q/K/V

// Workspace layout (shorts):
//  [0,2M)   Qh bf16 [n,h,l,d]  (PRE-SCALED by log2(e)/sqrt(32))
//  [2M,4M)  Kh bf16 [n,h,l,d]
//  [4M,6M)  Vt bf16 [n,h,d,l]
//  [6M,8M)  O2b bf16 [tok][256]
//  [8M,12.2M)  Xb bf16 [tok][512]
//  [12.25M, +393216)  Wb bf16 (Wq|Wk|Wv)
//  [+131072]          Wfcb bf16

typedef short short8 __attribute__((ext_vector_type(8)));   // 8 bf16 (4 VGPRs)
typedef short short4v __attribute__((ext_vector_type(4)));  // 4 bf16 (2 VGPRs)
typedef float floatx4 __attribute__((ext_vector_type(4)));  // MFMA C/D frag

constexpr size_t XB_OFF  = 8u * 1024 * 1024;        // shorts
constexpr size_t WB_OFF  = 12536832;                // shorts, 16B aligned
constexpr size_t WFCB_OFF = WB_OFF + 3 * 131072;

constexpr float C1 = 0.25505654f;  // log2(e)/sqrt(32), folded into Qh at projection

__device__ inline short f2bf(float x) {                     // RNE f32->bf16
  unsigned u = __builtin_bit_cast(unsigned, x);
  unsigned r = (u + 0x7FFFu + ((u >> 16) & 1u)) >> 16;
  return (short)r;
}

// K=16 bf16 MFMA: A[m=lane&15][k=quad*4+j], B[k=quad*4+j][n=lane&15], C/D as usual.
#if __has_builtin(__builtin_amdgcn_mfma_f32_16x16x16bf16_1k)
#define MFMA16(a, b, c) __builtin_amdgcn_mfma_f32_16x16x16bf16_1k(a, b, c, 0, 0, 0)
#else
__device__ inline floatx4 mfma16_asm(short4v a, short4v b, floatx4 c) {
  asm volatile("v_mfma_f32_16x16x16_bf16 %0, %1, %2, %3\n\ts_nop 4"
               : "=v"(c) : "v"(a), "v"(b), "0"(c));
  return c;
}
#define MFMA16(a, b, c) mfma16_asm(a, b, c)
#endif

// ---------------- Weight pre-convert: fp32 -> bf16 ----------------
__global__ __launch_bounds__(256) void cvtw_kernel(
    const float* __restrict__ Wq, const float* __restrict__ Wk,
    const float* __restrict__ Wv, const float* __restrict__ Wfc,
    short* __restrict__ Wb, short* __restrict__ Wfcb)
{
  const int z = blockIdx.y;
  const float* src = z == 0 ? Wq : (z == 1 ? Wk : (z == 2 ? Wv : Wfc));
  short* dst = z < 3 ? Wb + (size_t)z * 131072 : Wfcb;
  const int idx = (blockIdx.x * 256 + threadIdx.x) * 4;   // 131072 elems, grid.x=128
  float4 x = *(const float4*)&src[idx];
  *(short4v*)&dst[idx] = (short4v){f2bf(x.x), f2bf(x.y), f2bf(x.z), f2bf(x.w)};
}

// ---------------- Projection (bf16 MFMA, reg-double-buffered) ----------------
// grid (TTOK/64, INNER/64, 3), block 256 = 4 waves. Q output pre-scaled by C1.
__global__ __launch_bounds__(256) void proj_kernel(
    const float* __restrict__ q, const float* __restrict__ k, const float* __restrict__ v,
    const short* __restrict__ Wb,
    const float* __restrict__ bq, const float* __restrict__ bk,
    const float* __restrict__ bv,
    short* __restrict__ ws)
{
  const int mat = blockIdx.z;
  const float* X    = mat == 0 ? q  : (mat == 1 ? k  : v);
  const short* W    = Wb + (size_t)mat * 131072;
  const float* bias = mat == 0 ? bq : (mat == 1 ? bk : bv);
  short* outp = ws + (size_t)mat * HEAD_ELEMS;

  const int t0 = blockIdx.x * 64;
  const int c0 = blockIdx.y * 64;
  const int tid = threadIdx.x;
  const int col = tid & 15;
  const int quad = (tid & 63) >> 4;
  const int w = tid >> 6;

  __shared__ short Xs[64 * 136];
  __shared__ short Wsh[64 * 136];

  floatx4 acc[4];
#pragma unroll
  for (int nj = 0; nj < 4; ++nj) acc[nj] = (floatx4){0.f, 0.f, 0.f, 0.f};

  float4 xr[8];
  short8 wr[4];
  auto loadX = [&](int k0) {
#pragma unroll
    for (int j = 0; j < 8; ++j) {
      const int i = tid + j * 256, row = i >> 5, c4 = i & 31;
      xr[j] = *(const float4*)&X[(size_t)(t0 + row) * DM + k0 + c4 * 4];
    }
  };
  auto loadW = [&](int k0) {
#pragma unroll
    for (int j = 0; j < 4; ++j) {
      const int s = tid + j * 256, row = s >> 4, k8 = s & 15;
      wr[j] = *(const short8*)&W[(size_t)(c0 + row) * DM + k0 + k8 * 8];
    }
  };

  loadX(0);
  loadW(0);

  for (int kc = 0; kc < 4; ++kc) {
#pragma unroll
    for (int j = 0; j < 8; ++j) {
      const int i = tid + j * 256, row = i >> 5, c4 = i & 31;
      *(short4v*)&Xs[row * 136 + c4 * 4] =
          (short4v){f2bf(xr[j].x), f2bf(xr[j].y), f2bf(xr[j].z), f2bf(xr[j].w)};
    }
#pragma unroll
    for (int j = 0; j < 4; ++j) {
      const int s = tid + j * 256, row = s >> 4, k8 = s & 15;
      *(short8*)&Wsh[row * 136 + k8 * 8] = wr[j];
    }
    __syncthreads();
    if (kc < 3) {                       // prefetch next chunk while MFMAs run
      loadX((kc + 1) * 128);
      loadW((kc + 1) * 128);
    }
#pragma unroll
    for (int ks = 0; ks < 4; ++ks) {
      short8 a = *(const short8*)&Xs[(w * 16 + col) * 136 + ks * 32 + quad * 8];
#pragma unroll
      for (int nj = 0; nj < 4; ++nj) {
        short8 b = *(const short8*)&Wsh[(nj * 16 + col) * 136 + ks * 32 + quad * 8];
        acc[nj] = __builtin_amdgcn_mfma_f32_16x16x32_bf16(a, b, acc[nj], 0, 0, 0);
      }
    }
    __syncthreads();
  }

#pragma unroll
  for (int nj = 0; nj < 4; ++nj) {
#pragma unroll
    for (int r = 0; r < 4; ++r) {
      const int t = t0 + w * 16 + quad * 4 + r;
      const int n = t >> 11, ll = t & (Ln - 1);
      const int c = c0 + nj * 16 + col;
      const int d = c >> 3, h = c & 7;           // head is FASTEST dim of proj col
      float pv = acc[nj][r] + bias[c];
      if (mat == 0) pv *= C1;                    // fold softmax scale into Q
      const short val = f2bf(pv);
      if (mat < 2)
        outp[((size_t)(n * NH + h) * Ln + ll) * DKv + d] = val;   // [n,h,l,d]
      else
        outp[((size_t)(n * NH + h) * DKv + d) * Ln + ll] = val;   // [n,h,d,l]
    }
  }
}

// ---------------- Attention: register-P flash, 32 q/wave, de-conflicted K pitch ----------------
// grid (Ln/128, Bn*NH), block 256 = 4 waves, 32 q per wave (2 sub-tiles). St = K·Q^T
// (16x16x32); P in registers; O^T = V^T·P (16x16x16). K/V LDS frag reads amortized over
// 2x q-work. Ks pitch 40 (20 dwords/row): frag-read banks 4*(5*col mod 8)+4q -> <=2-way.
// Vs pitch 72: b64 reads 2-way (free). Double-buffered, 1 barrier/chunk.
__global__ __launch_bounds__(256) void attn_kernel(const short* __restrict__ ws,
                                                   short* __restrict__ O2b)
{
  const int bh = blockIdx.y;
  const int n = bh >> 3, h = bh & 7;
  const int tid = threadIdx.x;
  const int col = tid & 15;
  const int quad = (tid & 63) >> 4;
  const int w = tid >> 6;
  const int qb = blockIdx.x * 128 + w * 32;        // this wave's first q row

  const short* Qh = ws;
  const short* Kg = ws + HEAD_ELEMS + (size_t)bh * Ln * DKv;      // [l][d]
  const short* Vg = ws + 2 * HEAD_ELEMS + (size_t)bh * DKv * Ln;  // [d][l]

  __shared__ short Ks[2][64 * 40];   // [key][d], pitch 40
  __shared__ short Vs[2][32 * 72];   // [d][key], pitch 72

  // Q as B-frags (pre-scaled by C1): B[k=d=quad*8+j][n=q=lane&15]
  short8 aq[2];
#pragma unroll
  for (int si = 0; si < 2; ++si)
    aq[si] = *(const short8*)&Qh[(size_t)bh * Ln * DKv +
                                 (size_t)(qb + si * 16 + col) * DKv + quad * 8];

  float lsum[2] = {0.f, 0.f};
  floatx4 o[2][2];
#pragma unroll
  for (int si = 0; si < 2; ++si)
#pragma unroll
    for (int dt = 0; dt < 2; ++dt) o[si][dt] = (floatx4){0.f, 0.f, 0.f, 0.f};

  const int vd = tid >> 3, vkb = tid & 7;
  const int krow = tid >> 2, kj = tid & 3;         // K staging: row, 8-short chunk
  short8 kr = *(const short8*)(Kg + tid * 8);
  short8 vr = *(const short8*)(Vg + (size_t)vd * Ln + vkb * 8);

  for (int kt = 0; kt < 32; ++kt) {
    short* ksb = Ks[kt & 1];
    short* vsb = Vs[kt & 1];
    *(short8*)&ksb[krow * 40 + kj * 8] = kr;
    *(short8*)&vsb[vd * 72 + vkb * 8] = vr;
    __syncthreads();
    if (kt < 31) {                       // prefetch next chunk into registers
      kr = *(const short8*)(Kg + (size_t)(kt + 1) * 2048 + tid * 8);
      vr = *(const short8*)(Vg + (size_t)vd * Ln + (kt + 1) * 64 + vkb * 8);
    }

    // St tiles: rows = keys (quad*4+r), cols = q (lane&15); already log2-scaled
    floatx4 s[2][4];
    const floatx4 z4 = {0.f, 0.f, 0.f, 0.f};
#pragma unroll
    for (int ks = 0; ks < 4; ++ks) {
      short8 kf = *(const short8*)&ksb[(ks * 16 + col) * 40 + quad * 8];
      s[0][ks] = __builtin_amdgcn_mfma_f32_16x16x32_bf16(kf, aq[0], z4, 0, 0, 0);
      s[1][ks] = __builtin_amdgcn_mfma_f32_16x16x32_bf16(kf, aq[1], z4, 0, 0, 0);
    }

    // p = exp2(s); accumulate l; pack to bf16 B-frags (truncating v_perm)
    short4v pf[2][4];
#pragma unroll
    for (int si = 0; si < 2; ++si) {
#pragma unroll
      for (int ks = 0; ks < 4; ++ks) {
        float p0 = __builtin_amdgcn_exp2f(s[si][ks][0]);
        float p1 = __builtin_amdgcn_exp2f(s[si][ks][1]);
        float p2 = __builtin_amdgcn_exp2f(s[si][ks][2]);
        float p3 = __builtin_amdgcn_exp2f(s[si][ks][3]);
        lsum[si] += (p0 + p1) + (p2 + p3);
        unsigned u0 = __builtin_amdgcn_perm(__builtin_bit_cast(unsigned, p1),
                                            __builtin_bit_cast(unsigned, p0), 0x07060302u);
        unsigned u1 = __builtin_amdgcn_perm(__builtin_bit_cast(unsigned, p3),
                                            __builtin_bit_cast(unsigned, p2), 0x07060302u);
        uint2 uu = make_uint2(u0, u1);
        pf[si][ks] = __builtin_bit_cast(short4v, uu);
      }
    }

    // O^T += V^T P : V frags shared across both q sub-tiles
#pragma unroll
    for (int ks = 0; ks < 4; ++ks) {
      short4v va0 = *(const short4v*)&vsb[col * 72 + ks * 16 + quad * 4];
      short4v va1 = *(const short4v*)&vsb[(16 + col) * 72 + ks * 16 + quad * 4];
#pragma unroll
      for (int si = 0; si < 2; ++si) {
        o[si][0] = MFMA16(va0, pf[si][ks], o[si][0]);
        o[si][1] = MFMA16(va1, pf[si][ks], o[si][1]);
      }
    }
  }

  // l: cross-quad reduce; normalize; write O^T (col = q, row = quad*4+r = d)
#pragma unroll
  for (int si = 0; si < 2; ++si) {
    float l = lsum[si];
    l += __shfl_xor(l, 16);
    l += __shfl_xor(l, 32);
    const float inv = 1.f / l;
    const int qi = qb + si * 16 + col;
    short* dst = &O2b[((size_t)n * Ln + qi) * INNER + h * DKv];
#pragma unroll
    for (int dt = 0; dt < 2; ++dt)
#pragma unroll
      for (int r = 0; r < 4; ++r)
        dst[dt * 16 + quad * 4 + r] = f2bf(o[si][dt][r] * inv);
  }
}

// ---------------- FC (bf16 MFMA): Xb = bf16(O2b @ Wfc^T + bfc + q) ----------------
__global__ __launch_bounds__(256) void fc_kernel(
    const short* __restrict__ O2b, const short* __restrict__ Wfcb,
    const float* __restrict__ bfc, const float* __restrict__ qin,
    short* __restrict__ Xb)
{
  const int t0 = blockIdx.x * 64;
  const int c0 = blockIdx.y * 64;
  const int tid = threadIdx.x;
  const int col = tid & 15;
  const int quad = (tid & 63) >> 4;
  const int w = tid >> 6;

  __shared__ short As[64 * 264];
  __shared__ short Bs[64 * 264];

  for (int i = tid; i < 2048; i += 256) {
    const int row = i >> 5, k8 = i & 31;
    *(short8*)&As[row * 264 + k8 * 8] =
        *(const short8*)&O2b[(size_t)(t0 + row) * INNER + k8 * 8];
    *(short8*)&Bs[row * 264 + k8 * 8] =
        *(const short8*)&Wfcb[(size_t)(c0 + row) * INNER + k8 * 8];
  }
  __syncthreads();

  floatx4 acc[4];
#pragma unroll
  for (int nj = 0; nj < 4; ++nj) acc[nj] = (floatx4){0.f, 0.f, 0.f, 0.f};

#pragma unroll
  for (int ks = 0; ks < 8; ++ks) {
    short8 a = *(const short8*)&As[(w * 16 + col) * 264 + ks * 32 + quad * 8];
#pragma unroll
    for (int nj = 0; nj < 4; ++nj) {
      short8 b = *(const short8*)&Bs[(nj * 16 + col) * 264 + ks * 32 + quad * 8];
      acc[nj] = __builtin_amdgcn_mfma_f32_16x16x32_bf16(a, b, acc[nj], 0, 0, 0);
    }
  }

#pragma unroll
  for (int nj = 0; nj < 4; ++nj) {
#pragma unroll
    for (int r = 0; r < 4; ++r) {
      const int t = t0 + w * 16 + quad * 4 + r;
      const int c = c0 + nj * 16 + col;
      Xb[(size_t)t * DM + c] = f2bf(acc[nj][r] + bfc[c] + qin[(size_t)t * DM + c]);
    }
  }
}

// ---------------- LayerNorm over bf16 Xb rows -> fp32 out ----------------
__global__ __launch_bounds__(256) void ln_kernel(
    const short* __restrict__ Xb, const float* __restrict__ gamma,
    const float* __restrict__ beta, float* __restrict__ outp)
{
  const int t = blockIdx.x * 4 + (threadIdx.x >> 6);
  const int lane = threadIdx.x & 63;

  short8 xs = *(const short8*)&Xb[(size_t)t * DM + lane * 8];
  float x[8];
#pragma unroll
  for (int j = 0; j < 8; ++j)
    x[j] = __builtin_bit_cast(float, ((unsigned)(unsigned short)xs[j]) << 16);

  float s1 = 0.f, s2 = 0.f;
#pragma unroll
  for (int j = 0; j < 8; ++j) { s1 += x[j]; s2 += x[j] * x[j]; }
#pragma unroll
  for (int off = 32; off >= 1; off >>= 1) {
    s1 += __shfl_xor(s1, off);
    s2 += __shfl_xor(s2, off);
  }
  const float mean = s1 * (1.f / 512.f);
  const float var = s2 * (1.f / 512.f) - mean * mean;
  const float rstd = rsqrtf(var + 1e-5f);

  float4 g0 = *(const float4*)&gamma[lane * 8];
  float4 g1 = *(const float4*)&gamma[lane * 8 + 4];
  float4 b0 = *(const float4*)&beta[lane * 8];
  float4 b1 = *(const float4*)&beta[lane * 8 + 4];

  float4 y0, y1;
  y0.x = g0.x * (x[0] - mean) * rstd + b0.x;
  y0.y = g0.y * (x[1] - mean) * rstd + b0.y;
  y0.z = g0.z * (x[2] - mean) * rstd + b0.z;
  y0.w = g0.w * (x[3] - mean) * rstd + b0.w;
  y1.x = g1.x * (x[4] - mean) * rstd + b1.x;
  y1.y = g1.y * (x[5] - mean) * rstd + b1.y;
  y1.z = g1.z * (x[6] - mean) * rstd + b1.z;
  y1.w = g1.w * (x[7] - mean) * rstd + b1.w;

  float* drow = &outp[(size_t)t * DM + lane * 8];
  *(float4*)&drow[0] = y0;
  *(float4*)&drow[4] = y1;
}

extern "C" void kernel_launch(void* const* d_in, const int* in_sizes, int n_in,
                              void* d_out, int out_size, void* d_ws, size_t ws_size,
                              hipStream_t stream) {
  const float* q     = (const float*)d_in[0];
  const float* k     = (const float*)d_in[1];
  const float* v     = (const float*)d_in[2];
  const float* Wq    = (const float*)d_in[3];
  const float* bq    = (const float*)d_in[4];
  const float* Wk    = (const float*)d_in[5];
  const float* bk    = (const float*)d_in[6];
  const float* Wv    = (const float*)d_in[7];
  const float* bv    = (const float*)d_in[8];
  const float* Wfc   = (const float*)d_in[9];
  const float* bfc   = (const float*)d_in[10];
  const float* gamma = (const float*)d_in[11];
  const float* beta  = (const float*)d_in[12];

  short* wsS  = (short*)d_ws;
  short* O2b  = wsS + 3 * HEAD_ELEMS;
  short* Xb   = wsS + XB_OFF;
  short* Wb   = wsS + WB_OFF;
  short* Wfcb = wsS + WFCB_OFF;

  cvtw_kernel<<<dim3(128, 4), 256, 0, stream>>>(Wq, Wk, Wv, Wfc, Wb, Wfcb);

  dim3 gp(TTOK / 64, INNER / 64, 3);
  proj_kernel<<<gp, 256, 0, stream>>>(q, k, v, Wb, bq, bk, bv, wsS);

  dim3 gatt(Ln / 128, Bn * NH);
  attn_kernel<<<gatt, 256, 0, stream>>>(wsS, O2b);

  dim3 gfc(TTOK / 64, DM / 64);
  fc_kernel<<<gfc, 256, 0, stream>>>(O2b, Wfcb, bfc, q, Xb);

  ln_kernel<<<TTOK / 4, 256, 0, stream>>>(Xb, gamma, beta, (float*)d_out);
}

// Round 8
// 182.679 us; speedup vs baseline: 1.0631x; 1.0282x over previous
//
#include <hip/hip_runtime.h>
#include <math.h>

// Problem constants (fixed by reference)
constexpr int Bn = 4, Ln = 2048, DM = 512, NH = 8, DKv = 32, INNER = 256;
constexpr int TTOK = Bn * Ln;                              // 8192 tokens
constexpr size_t HEAD_ELEMS = (size_t)Bn * NH * Ln * DKv;  // 2,097,152 elems per Q/K/V

// Workspace layout (shorts):
//  [0,2M)   Qh bf16 [n,h,l,d]  (PRE-SCALED by log2(e)/sqrt(32))
//  [2M,4M)  Kh bf16 [n,h,l,d]
//  [4M,6M)  Vt bf16 [n,h,d,l]
//  [6M,8M)  O2b bf16 [tok][256]
//  [8M,12.2M)  Xb bf16 [tok][512]
//  [12.25M, +393216)  Wb bf16 (Wq|Wk|Wv)
//  [+131072]          Wfcb bf16

typedef short short8 __attribute__((ext_vector_type(8)));   // 8 bf16 (4 VGPRs)
typedef short short4v __attribute__((ext_vector_type(4)));  // 4 bf16 (2 VGPRs)
typedef float floatx4 __attribute__((ext_vector_type(4)));  // 16x16 MFMA C/D frag
typedef float floatx16 __attribute__((ext_vector_type(16))); // 32x32 MFMA C/D frag

constexpr size_t XB_OFF  = 8u * 1024 * 1024;        // shorts
constexpr size_t WB_OFF  = 12536832;                // shorts, 16B aligned
constexpr size_t WFCB_OFF = WB_OFF + 3 * 131072;

constexpr float C1 = 0.25505654f;  // log2(e)/sqrt(32), folded into Qh at projection

__device__ inline short f2bf(float x) {                     // RNE f32->bf16
  unsigned u = __builtin_bit_cast(unsigned, x);
  unsigned r = (u + 0x7FFFu + ((u >> 16) & 1u)) >> 16;
  return (short)r;
}

// ---------------- Weight pre-convert: fp32 -> bf16 ----------------
__global__ __launch_bounds__(256) void cvtw_kernel(
    const float* __restrict__ Wq, const float* __restrict__ Wk,
    const float* __restrict__ Wv, const float* __restrict__ Wfc,
    short* __restrict__ Wb, short* __restrict__ Wfcb)
{
  const int z = blockIdx.y;
  const float* src = z == 0 ? Wq : (z == 1 ? Wk : (z == 2 ? Wv : Wfc));
  short* dst = z < 3 ? Wb + (size_t)z * 131072 : Wfcb;
  const int idx = (blockIdx.x * 256 + threadIdx.x) * 4;   // 131072 elems, grid.x=128
  float4 x = *(const float4*)&src[idx];
  *(short4v*)&dst[idx] = (short4v){f2bf(x.x), f2bf(x.y), f2bf(x.z), f2bf(x.w)};
}

// ---------------- Projection (bf16 MFMA, reg-double-buffered) ----------------
// grid (TTOK/64, INNER/64, 3), block 256 = 4 waves. Q output pre-scaled by C1.
__global__ __launch_bounds__(256) void proj_kernel(
    const float* __restrict__ q, const float* __restrict__ k, const float* __restrict__ v,
    const short* __restrict__ Wb,
    const float* __restrict__ bq, const float* __restrict__ bk,
    const float* __restrict__ bv,
    short* __restrict__ ws)
{
  const int mat = blockIdx.z;
  const float* X    = mat == 0 ? q  : (mat == 1 ? k  : v);
  const short* W    = Wb + (size_t)mat * 131072;
  const float* bias = mat == 0 ? bq : (mat == 1 ? bk : bv);
  short* outp = ws + (size_t)mat * HEAD_ELEMS;

  const int t0 = blockIdx.x * 64;
  const int c0 = blockIdx.y * 64;
  const int tid = threadIdx.x;
  const int col = tid & 15;
  const int quad = (tid & 63) >> 4;
  const int w = tid >> 6;

  __shared__ short Xs[64 * 136];
  __shared__ short Wsh[64 * 136];

  floatx4 acc[4];
#pragma unroll
  for (int nj = 0; nj < 4; ++nj) acc[nj] = (floatx4){0.f, 0.f, 0.f, 0.f};

  float4 xr[8];
  short8 wr[4];
  auto loadX = [&](int k0) {
#pragma unroll
    for (int j = 0; j < 8; ++j) {
      const int i = tid + j * 256, row = i >> 5, c4 = i & 31;
      xr[j] = *(const float4*)&X[(size_t)(t0 + row) * DM + k0 + c4 * 4];
    }
  };
  auto loadW = [&](int k0) {
#pragma unroll
    for (int j = 0; j < 4; ++j) {
      const int s = tid + j * 256, row = s >> 4, k8 = s & 15;
      wr[j] = *(const short8*)&W[(size_t)(c0 + row) * DM + k0 + k8 * 8];
    }
  };

  loadX(0);
  loadW(0);

  for (int kc = 0; kc < 4; ++kc) {
#pragma unroll
    for (int j = 0; j < 8; ++j) {
      const int i = tid + j * 256, row = i >> 5, c4 = i & 31;
      *(short4v*)&Xs[row * 136 + c4 * 4] =
          (short4v){f2bf(xr[j].x), f2bf(xr[j].y), f2bf(xr[j].z), f2bf(xr[j].w)};
    }
#pragma unroll
    for (int j = 0; j < 4; ++j) {
      const int s = tid + j * 256, row = s >> 4, k8 = s & 15;
      *(short8*)&Wsh[row * 136 + k8 * 8] = wr[j];
    }
    __syncthreads();
    if (kc < 3) {                       // prefetch next chunk while MFMAs run
      loadX((kc + 1) * 128);
      loadW((kc + 1) * 128);
    }
#pragma unroll
    for (int ks = 0; ks < 4; ++ks) {
      short8 a = *(const short8*)&Xs[(w * 16 + col) * 136 + ks * 32 + quad * 8];
#pragma unroll
      for (int nj = 0; nj < 4; ++nj) {
        short8 b = *(const short8*)&Wsh[(nj * 16 + col) * 136 + ks * 32 + quad * 8];
        acc[nj] = __builtin_amdgcn_mfma_f32_16x16x32_bf16(a, b, acc[nj], 0, 0, 0);
      }
    }
    __syncthreads();
  }

#pragma unroll
  for (int nj = 0; nj < 4; ++nj) {
#pragma unroll
    for (int r = 0; r < 4; ++r) {
      const int t = t0 + w * 16 + quad * 4 + r;
      const int n = t >> 11, ll = t & (Ln - 1);
      const int c = c0 + nj * 16 + col;
      const int d = c >> 3, h = c & 7;           // head is FASTEST dim of proj col
      float pv = acc[nj][r] + bias[c];
      if (mat == 0) pv *= C1;                    // fold softmax scale into Q
      const short val = f2bf(pv);
      if (mat < 2)
        outp[((size_t)(n * NH + h) * Ln + ll) * DKv + d] = val;   // [n,h,l,d]
      else
        outp[((size_t)(n * NH + h) * DKv + d) * Ln + ll] = val;   // [n,h,d,l]
    }
  }
}

// ---------------- Attention: 32x32 MFMA register-P flash ----------------
// grid (Ln/128, Bn*NH), block 256 = 4 waves, 32 q per wave (q = lane&31).
// St (32key x 32q) = K·Q^T via 2x mfma_32x32x16; K staged with bit2<->bit3 key
// permutation per 32-group so St C-regs 0..7 / 8..15 are exactly the B-frags of the
// PV MFMAs (keys 8*half+j in reg order). P stays in registers; O^T = V^T·P and
// l = ones^T·P via mfma_32x32x16 (l on the MFMA pipe frees the VALU pipe).
// 128-key chunks, LDS double-buffered, one barrier per chunk. All LDS patterns <=2-way.
__global__ __launch_bounds__(256) void attn_kernel(const short* __restrict__ ws,
                                                   short* __restrict__ O2b)
{
  const int bh = blockIdx.y;
  const int n = bh >> 3, h = bh & 7;
  const int tid = threadIdx.x;
  const int lane = tid & 63;
  const int col = lane & 31;        // q (and m) index
  const int hf = lane >> 5;         // lane half: k-slot group
  const int w = tid >> 6;
  const int qi = blockIdx.x * 128 + w * 32 + col;   // this lane's q row

  const short* Qh = ws;
  const short* Kg = ws + HEAD_ELEMS + (size_t)bh * Ln * DKv;      // [l][d]
  const short* Vg = ws + 2 * HEAD_ELEMS + (size_t)bh * DKv * Ln;  // [d][l]

  __shared__ short Ks[2][128 * 40];   // [perm key][d], pitch 40
  __shared__ short Vs[2][32 * 136];   // [d][key natural], pitch 136

  // Q as B-frags (pre-scaled by C1): B[k=d=c*16+8*hf+j][n=q=col]
  short8 aq[2];
#pragma unroll
  for (int c = 0; c < 2; ++c)
    aq[c] = *(const short8*)&Qh[(size_t)bh * Ln * DKv + (size_t)qi * DKv + c * 16 + hf * 8];

  short8 ones;
#pragma unroll
  for (int j = 0; j < 8; ++j) ones[j] = (short)0x3F80;  // bf16 1.0

  floatx16 o, ol;
#pragma unroll
  for (int i = 0; i < 16; ++i) { o[i] = 0.f; ol[i] = 0.f; }

  // K staging: thread (kg,khalf); LDS row = kg with bits 2,3 swapped (32-group perm)
  const int kg = tid >> 1, khalf = tid & 1;
  const int krow = (kg & ~12) | ((kg & 4) << 1) | ((kg & 8) >> 1);
  const int kst = krow * 40 + khalf * 16;
  // V staging: thread (vd, vkb) -> natural order
  const int vd = tid >> 3, vkb = tid & 7;
  const int vst = vd * 136 + vkb * 16;

  short8 kr0 = *(const short8*)(Kg + kg * 32 + khalf * 16);
  short8 kr1 = *(const short8*)(Kg + kg * 32 + khalf * 16 + 8);
  short8 vr0 = *(const short8*)(Vg + (size_t)vd * Ln + vkb * 16);
  short8 vr1 = *(const short8*)(Vg + (size_t)vd * Ln + vkb * 16 + 8);

  for (int kt = 0; kt < 16; ++kt) {
    short* ksb = Ks[kt & 1];
    short* vsb = Vs[kt & 1];
    *(short8*)&ksb[kst] = kr0;
    *(short8*)&ksb[kst + 8] = kr1;
    *(short8*)&vsb[vst] = vr0;
    *(short8*)&vsb[vst + 8] = vr1;
    __syncthreads();
    if (kt < 15) {                      // register prefetch of next 128-key chunk
      kr0 = *(const short8*)(Kg + (size_t)(kt + 1) * 4096 + kg * 32 + khalf * 16);
      kr1 = *(const short8*)(Kg + (size_t)(kt + 1) * 4096 + kg * 32 + khalf * 16 + 8);
      vr0 = *(const short8*)(Vg + (size_t)vd * Ln + (kt + 1) * 128 + vkb * 16);
      vr1 = *(const short8*)(Vg + (size_t)vd * Ln + (kt + 1) * 128 + vkb * 16 + 8);
    }

#pragma unroll
    for (int cc = 0; cc < 4; ++cc) {    // 32-key sub-chunks
      // St = K·Q^T  (A rows = permuted-key LDS rows; contraction over d=32)
      floatx16 st;
#pragma unroll
      for (int i = 0; i < 16; ++i) st[i] = 0.f;
      short8 kf0 = *(const short8*)&ksb[(cc * 32 + col) * 40 + hf * 8];
      short8 kf1 = *(const short8*)&ksb[(cc * 32 + col) * 40 + 16 + hf * 8];
      st = __builtin_amdgcn_mfma_f32_32x32x16_bf16(kf0, aq[0], st, 0, 0, 0);
      st = __builtin_amdgcn_mfma_f32_32x32x16_bf16(kf1, aq[1], st, 0, 0, 0);

      // p = exp2(st) (already log2-scaled); pack regs 0..7 / 8..15 -> B-frags
      float p[16];
#pragma unroll
      for (int i = 0; i < 16; ++i) p[i] = __builtin_amdgcn_exp2f(st[i]);
      short8 pf[2];
#pragma unroll
      for (int half = 0; half < 2; ++half) {
        unsigned u[4];
#pragma unroll
        for (int j = 0; j < 4; ++j)
          u[j] = __builtin_amdgcn_perm(
              __builtin_bit_cast(unsigned, p[half * 8 + 2 * j + 1]),
              __builtin_bit_cast(unsigned, p[half * 8 + 2 * j]), 0x07060302u);
        uint4 uu = make_uint4(u[0], u[1], u[2], u[3]);
        pf[half] = __builtin_bit_cast(short8, uu);
      }

      // l += ones^T · P   (all D rows identical = row-sum per q)
      ol = __builtin_amdgcn_mfma_f32_32x32x16_bf16(ones, pf[0], ol, 0, 0, 0);
      ol = __builtin_amdgcn_mfma_f32_32x32x16_bf16(ones, pf[1], ol, 0, 0, 0);

      // O^T += V^T · P  (A = V natural order: keys cc*32 + 16*half + 8*hf + j)
      short8 va0 = *(const short8*)&vsb[col * 136 + cc * 32 + hf * 8];
      short8 va1 = *(const short8*)&vsb[col * 136 + cc * 32 + 16 + hf * 8];
      o = __builtin_amdgcn_mfma_f32_32x32x16_bf16(va0, pf[0], o, 0, 0, 0);
      o = __builtin_amdgcn_mfma_f32_32x32x16_bf16(va1, pf[1], o, 0, 0, 0);
    }
  }

  // epilogue: l = any ol reg (rows identical); normalize; write O^T
  const float inv = 1.f / ol[0];
  short* dst = &O2b[((size_t)n * Ln + qi) * INNER + h * DKv];
#pragma unroll
  for (int g4 = 0; g4 < 4; ++g4) {      // regs 4g4..4g4+3 -> d = 8*g4 + 4*hf + (0..3)
    short4v pk = (short4v){f2bf(o[g4 * 4 + 0] * inv), f2bf(o[g4 * 4 + 1] * inv),
                           f2bf(o[g4 * 4 + 2] * inv), f2bf(o[g4 * 4 + 3] * inv)};
    *(short4v*)&dst[8 * g4 + 4 * hf] = pk;
  }
}

// ---------------- FC (bf16 MFMA): Xb = bf16(O2b @ Wfc^T + bfc + q) ----------------
__global__ __launch_bounds__(256) void fc_kernel(
    const short* __restrict__ O2b, const short* __restrict__ Wfcb,
    const float* __restrict__ bfc, const float* __restrict__ qin,
    short* __restrict__ Xb)
{
  const int t0 = blockIdx.x * 64;
  const int c0 = blockIdx.y * 64;
  const int tid = threadIdx.x;
  const int col = tid & 15;
  const int quad = (tid & 63) >> 4;
  const int w = tid >> 6;

  __shared__ short As[64 * 264];
  __shared__ short Bs[64 * 264];

  for (int i = tid; i < 2048; i += 256) {
    const int row = i >> 5, k8 = i & 31;
    *(short8*)&As[row * 264 + k8 * 8] =
        *(const short8*)&O2b[(size_t)(t0 + row) * INNER + k8 * 8];
    *(short8*)&Bs[row * 264 + k8 * 8] =
        *(const short8*)&Wfcb[(size_t)(c0 + row) * INNER + k8 * 8];
  }
  __syncthreads();

  floatx4 acc[4];
#pragma unroll
  for (int nj = 0; nj < 4; ++nj) acc[nj] = (floatx4){0.f, 0.f, 0.f, 0.f};

#pragma unroll
  for (int ks = 0; ks < 8; ++ks) {
    short8 a = *(const short8*)&As[(w * 16 + col) * 264 + ks * 32 + quad * 8];
#pragma unroll
    for (int nj = 0; nj < 4; ++nj) {
      short8 b = *(const short8*)&Bs[(nj * 16 + col) * 264 + ks * 32 + quad * 8];
      acc[nj] = __builtin_amdgcn_mfma_f32_16x16x32_bf16(a, b, acc[nj], 0, 0, 0);
    }
  }

#pragma unroll
  for (int nj = 0; nj < 4; ++nj) {
#pragma unroll
    for (int r = 0; r < 4; ++r) {
      const int t = t0 + w * 16 + quad * 4 + r;
      const int c = c0 + nj * 16 + col;
      Xb[(size_t)t * DM + c] = f2bf(acc[nj][r] + bfc[c] + qin[(size_t)t * DM + c]);
    }
  }
}

// ---------------- LayerNorm over bf16 Xb rows -> fp32 out ----------------
__global__ __launch_bounds__(256) void ln_kernel(
    const short* __restrict__ Xb, const float* __restrict__ gamma,
    const float* __restrict__ beta, float* __restrict__ outp)
{
  const int t = blockIdx.x * 4 + (threadIdx.x >> 6);
  const int lane = threadIdx.x & 63;

  short8 xs = *(const short8*)&Xb[(size_t)t * DM + lane * 8];
  float x[8];
#pragma unroll
  for (int j = 0; j < 8; ++j)
    x[j] = __builtin_bit_cast(float, ((unsigned)(unsigned short)xs[j]) << 16);

  float s1 = 0.f, s2 = 0.f;
#pragma unroll
  for (int j = 0; j < 8; ++j) { s1 += x[j]; s2 += x[j] * x[j]; }
#pragma unroll
  for (int off = 32; off >= 1; off >>= 1) {
    s1 += __shfl_xor(s1, off);
    s2 += __shfl_xor(s2, off);
  }
  const float mean = s1 * (1.f / 512.f);
  const float var = s2 * (1.f / 512.f) - mean * mean;
  const float rstd = rsqrtf(var + 1e-5f);

  float4 g0 = *(const float4*)&gamma[lane * 8];
  float4 g1 = *(const float4*)&gamma[lane * 8 + 4];
  float4 b0 = *(const float4*)&beta[lane * 8];
  float4 b1 = *(const float4*)&beta[lane * 8 + 4];

  float4 y0, y1;
  y0.x = g0.x * (x[0] - mean) * rstd + b0.x;
  y0.y = g0.y * (x[1] - mean) * rstd + b0.y;
  y0.z = g0.z * (x[2] - mean) * rstd + b0.z;
  y0.w = g0.w * (x[3] - mean) * rstd + b0.w;
  y1.x = g1.x * (x[4] - mean) * rstd + b1.x;
  y1.y = g1.y * (x[5] - mean) * rstd + b1.y;
  y1.z = g1.z * (x[6] - mean) * rstd + b1.z;
  y1.w = g1.w * (x[7] - mean) * rstd + b1.w;

  float* drow = &outp[(size_t)t * DM + lane * 8];
  *(float4*)&drow[0] = y0;
  *(float4*)&drow[4] = y1;
}

extern "C" void kernel_launch(void* const* d_in, const int* in_sizes, int n_in,
                              void* d_out, int out_size, void* d_ws, size_t ws_size,
                              hipStream_t stream) {
  const float* q     = (const float*)d_in[0];
  const float* k     = (const float*)d_in[1];
  const float* v     = (const float*)d_in[2];
  const float* Wq    = (const float*)d_in[3];
  const float* bq    = (const float*)d_in[4];
  const float* Wk    = (const float*)d_in[5];
  const float* bk    = (const float*)d_in[6];
  const float* Wv    = (const float*)d_in[7];
  const float* bv    = (const float*)d_in[8];
  const float* Wfc   = (const float*)d_in[9];
  const float* bfc   = (const float*)d_in[10];
  const float* gamma = (const float*)d_in[11];
  const float* beta  = (const float*)d_in[12];

  short* wsS  = (short*)d_ws;
  short* O2b  = wsS + 3 * HEAD_ELEMS;
  short* Xb   = wsS + XB_OFF;
  short* Wb   = wsS + WB_OFF;
  short* Wfcb = wsS + WFCB_OFF;

  cvtw_kernel<<<dim3(128, 4), 256, 0, stream>>>(Wq, Wk, Wv, Wfc, Wb, Wfcb);

  dim3 gp(TTOK / 64, INNER / 64, 3);
  proj_kernel<<<gp, 256, 0, stream>>>(q, k, v, Wb, bq, bk, bv, wsS);

  dim3 gatt(Ln / 128, Bn * NH);
  attn_kernel<<<gatt, 256, 0, stream>>>(wsS, O2b);

  dim3 gfc(TTOK / 64, DM / 64);
  fc_kernel<<<gfc, 256, 0, stream>>>(O2b, Wfcb, bfc, q, Xb);

  ln_kernel<<<TTOK / 4, 256, 0, stream>>>(Xb, gamma, beta, (float*)d_out);
}